// Round 1
// baseline (146.356 us; speedup 1.0000x reference)
//
#include <hip/hip_runtime.h>

// Problem constants (match reference)
#define BB 8
#define CC 128
#define HH 112
#define WW 112
#define TH 16                 // output rows per block; 112/16 = 7 tiles/plane
#define TILES_Y (HH / TH)     // 7

// LUT-based depthwise 3x3 conv, stride 1, pad 1.
// out[b,c,y,x] = ( sum_{tap} sign(t1,t2) * lut[|t1|,|t2|] ) / 1000
//   t1 = clip(round(w*1000), -255, 255)   (per channel/tap, constant)
//   t2 = clip(round(x_padded), -255, 255) (per pixel)
//   sign = +1 iff (t1>0 && t2>0) || (t1<0 && t2<0), else -1  (zero => -1)
//
// Strategy: per block = (b, c, row-tile).
//  - Build signed per-tap table tab[9][511] in LDS indexed by t2+255
//    (folds the whole sign rule + lut row gather; 18.4 KB).
//  - Quantize the input tile (+1 halo) once into LDS as uint16 index (4.1 KB).
//  - Inner loop: 9 LDS lookups + adds per output. Branch-free.
__global__ __launch_bounds__(256)
void approx_dconv_kernel(const float* __restrict__ x,
                         const float* __restrict__ w,
                         const float* __restrict__ lut,
                         float* __restrict__ out) {
    __shared__ float tab[9][512];                    // 511 used; 512 for addressing
    __shared__ unsigned short xq[TH + 2][WW + 2];    // quantized indices (t2+255)

    const int tid   = threadIdx.x;
    const int blk   = blockIdx.x;
    const int tileY = blk % TILES_Y;
    const int bc    = blk / TILES_Y;                 // b*CC + c
    const int c     = bc % CC;

    // ---- 1) build per-tap signed tables ----------------------------------
    #pragma unroll
    for (int t = 0; t < 9; ++t) {
        float t1 = rintf(w[c * 9 + t] * 1000.0f);
        t1 = fminf(fmaxf(t1, -255.0f), 255.0f);
        const int  i1 = (int)fabsf(t1);
        const bool p  = (t1 > 0.0f);
        const bool n  = (t1 < 0.0f);
        const float* lrow = lut + i1 * 256;
        for (int j = tid; j < 511; j += 256) {
            const int t2 = j - 255;
            const float v = lrow[abs(t2)];
            const bool pos = (p && t2 > 0) || (n && t2 < 0);
            tab[t][j] = pos ? v : -v;
        }
    }

    // ---- 2) quantize input tile (+halo) into LDS -------------------------
    const float* xp = x + (size_t)bc * (HH * WW);
    const int y0 = tileY * TH;                       // first output row
    for (int e = tid; e < (TH + 2) * (WW + 2); e += 256) {
        const int ry = e / (WW + 2);
        const int rx = e % (WW + 2);
        const int gy = y0 + ry - 1;
        const int gx = rx - 1;
        float v = 0.0f;                              // zero padding
        if (gy >= 0 && gy < HH && gx >= 0 && gx < WW) v = xp[gy * WW + gx];
        float t2 = rintf(v);
        t2 = fminf(fmaxf(t2, -255.0f), 255.0f);
        xq[ry][rx] = (unsigned short)((int)t2 + 255);
    }
    __syncthreads();

    // ---- 3) compute outputs ----------------------------------------------
    float* op = out + (size_t)bc * (HH * WW) + y0 * WW;
    for (int e = tid; e < TH * WW; e += 256) {
        const int oy = e / WW;
        const int ox = e % WW;
        float acc = 0.0f;
        #pragma unroll
        for (int ky = 0; ky < 3; ++ky) {
            #pragma unroll
            for (int kx = 0; kx < 3; ++kx) {
                acc += tab[ky * 3 + kx][xq[oy + ky][ox + kx]];
            }
        }
        op[oy * WW + ox] = acc * 0.001f;
    }
}

extern "C" void kernel_launch(void* const* d_in, const int* in_sizes, int n_in,
                              void* d_out, int out_size, void* d_ws, size_t ws_size,
                              hipStream_t stream) {
    const float* x   = (const float*)d_in[0];
    const float* w   = (const float*)d_in[1];
    const float* lut = (const float*)d_in[2];
    float* out = (float*)d_out;
    (void)in_sizes; (void)n_in; (void)out_size; (void)d_ws; (void)ws_size;

    const int grid = BB * CC * TILES_Y;              // 8*128*7 = 7168 blocks
    approx_dconv_kernel<<<grid, 256, 0, stream>>>(x, w, lut, out);
}

// Round 2
// 120.976 us; speedup vs baseline: 1.2098x; 1.2098x over previous
//
#include <hip/hip_runtime.h>

// Problem constants (match reference)
#define BB 8
#define CC 128
#define HH 112
#define WW 112
#define TH 56                  // output rows per block; 112/56 = 2 tiles/plane
#define TILES_Y (HH / TH)      // 2
#define XT (WW / 4)            // 28 x-tiles of 4 outputs each
#define PITCH 120              // u16 per xq row (240 B, 8B-aligned granules)
#define PITCH32 (PITCH / 2)

// LUT-based depthwise 3x3 conv, stride 1, pad 1.
//   t1 = clip(round(w*1000), -255, 255)   per channel/tap (constant)
//   t2 = clip(round(x_padded), -255, 255) per pixel
//   contribution = sign(t1,t2) * lut[|t1|,|t2|];  sign=+1 iff strictly same sign
//   out = sum(9 taps) / 1000
//
// Per block = (b, c, row-half-plane):
//  - tab[9][512]: signed per-tap table indexed by t2+255, mirror-filled from
//    one coalesced 256-float lut row read per tap (folds sign rule + gather).
//  - xq: quantized indices for the 56-row tile (+halo), u16, cols offset by +2
//    so 4-output groups read aligned 8B granules. float4 global loads.
//  - Compute: each thread produces 4 consecutive outputs -> 6 packed xq reads
//    + 36 random tab reads + float4 store.
__global__ __launch_bounds__(256)
void approx_dconv_kernel(const float* __restrict__ x,
                         const float* __restrict__ w,
                         const float* __restrict__ lut,
                         float* __restrict__ out) {
    __shared__ float tab[9][512];                         // 18432 B
    __shared__ unsigned int xq32[(TH + 2) * PITCH32];     // 13920 B

    const int tid   = threadIdx.x;
    const int blk   = blockIdx.x;
    const int tileY = blk % TILES_Y;
    const int bc    = blk / TILES_Y;
    const int c     = bc % CC;
    const int y0    = tileY * TH;

    // ---- 1) build signed per-tap tables (mirror fill) --------------------
    {
        const int i = tid;  // 0..255 == |t2|
        #pragma unroll
        for (int t = 0; t < 9; ++t) {
            float t1 = rintf(w[c * 9 + t] * 1000.0f);
            t1 = fminf(fmaxf(t1, -255.0f), 255.0f);
            const int  i1 = (int)fabsf(t1);
            const bool sp = (t1 > 0.0f);
            const bool sn = (t1 < 0.0f);
            const float v = lut[i1 * 256 + i];            // coalesced row read
            tab[t][255 + i] = (sp && i > 0) ? v : -v;     // t2 = +i
            tab[t][255 - i] = (sn && i > 0) ? v : -v;     // t2 = -i (i=0: dup)
        }
    }

    // ---- 2) quantize input tile (+halo) into LDS -------------------------
    // u16 col layout: col (gx+2) holds pixel gx; col 1 = left pad, col 114 =
    // right pad; cols 0,115.. are never consumed.
    const float* xp = x + (size_t)bc * (HH * WW);
    for (int e = tid; e < (TH + 2) * XT; e += 256) {
        const int r  = e / XT;
        const int k  = e % XT;
        const int gy = y0 + r - 1;
        unsigned int p0 = 0x00ff00ffu, p1 = 0x00ff00ffu;  // pad quant (idx 255)
        if (gy >= 0 && gy < HH) {
            const float4 v = *(const float4*)(xp + gy * WW + 4 * k);
            const int q0 = (int)fminf(fmaxf(rintf(v.x), -255.f), 255.f) + 255;
            const int q1 = (int)fminf(fmaxf(rintf(v.y), -255.f), 255.f) + 255;
            const int q2 = (int)fminf(fmaxf(rintf(v.z), -255.f), 255.f) + 255;
            const int q3 = (int)fminf(fmaxf(rintf(v.w), -255.f), 255.f) + 255;
            p0 = (unsigned)q0 | ((unsigned)q1 << 16);
            p1 = (unsigned)q2 | ((unsigned)q3 << 16);
        }
        xq32[r * PITCH32 + 2 * k + 1] = p0;               // u16 cols 4k+2,4k+3
        xq32[r * PITCH32 + 2 * k + 2] = p1;               // u16 cols 4k+4,4k+5
    }
    {   // halo columns (u16 writes; disjoint u32 granules from interior)
        unsigned short* xq16 = (unsigned short*)xq32;
        for (int r = tid; r < TH + 2; r += 256) {
            xq16[r * PITCH + 1]   = 255;                  // gx = -1
            xq16[r * PITCH + 114] = 255;                  // gx = 112
        }
    }
    __syncthreads();

    // ---- 3) compute: 4 outputs per thread --------------------------------
    float* op = out + (size_t)bc * (HH * WW) + y0 * WW;
    for (int e = tid; e < TH * XT; e += 256) {
        const int oy = e / XT;
        const int xt = e % XT;
        float a0 = 0.f, a1 = 0.f, a2 = 0.f, a3 = 0.f;
        #pragma unroll
        for (int r = 0; r < 3; ++r) {
            const unsigned int* q = &xq32[(oy + r) * PITCH32 + 2 * xt];
            const unsigned int w0 = q[0], w1 = q[1], w2 = q[2], w3 = q[3];
            // u16 cols 4xt+1 .. 4xt+6  (pixels gx = 4xt-1 .. 4xt+4)
            const int c1 = w0 >> 16;
            const int c2 = w1 & 0xffff;
            const int c3 = w1 >> 16;
            const int c4 = w2 & 0xffff;
            const int c5 = w2 >> 16;
            const int c6 = w3 & 0xffff;
            const float* t0 = tab[3 * r + 0];
            const float* t1 = tab[3 * r + 1];
            const float* t2 = tab[3 * r + 2];
            a0 += t0[c1] + t1[c2] + t2[c3];
            a1 += t0[c2] + t1[c3] + t2[c4];
            a2 += t0[c3] + t1[c4] + t2[c5];
            a3 += t0[c4] + t1[c5] + t2[c6];
        }
        float4 o;
        o.x = a0 * 0.001f; o.y = a1 * 0.001f;
        o.z = a2 * 0.001f; o.w = a3 * 0.001f;
        *(float4*)(op + oy * WW + 4 * xt) = o;
    }
}

extern "C" void kernel_launch(void* const* d_in, const int* in_sizes, int n_in,
                              void* d_out, int out_size, void* d_ws, size_t ws_size,
                              hipStream_t stream) {
    const float* x   = (const float*)d_in[0];
    const float* w   = (const float*)d_in[1];
    const float* lut = (const float*)d_in[2];
    float* out = (float*)d_out;
    (void)in_sizes; (void)n_in; (void)out_size; (void)d_ws; (void)ws_size;

    const int grid = BB * CC * TILES_Y;                   // 8*128*2 = 2048
    approx_dconv_kernel<<<grid, 256, 0, stream>>>(x, w, lut, out);
}